// Round 16
// baseline (206.994 us; speedup 1.0000x reference)
//
#include <hip/hip_runtime.h>

#define B_ 4
#define L_ 4096
#define D_ 1152
#define T_ (B_*L_)      // 16384 tokens
#define D3_ 384
#define H_ 16

typedef __attribute__((ext_vector_type(4))) float f32x4;
typedef __attribute__((ext_vector_type(8))) __bf16 bf16x8;
typedef __attribute__((ext_vector_type(8))) unsigned short u16x8;
typedef __attribute__((ext_vector_type(4))) unsigned short u16x4;

__device__ __forceinline__ unsigned short f2bf(float f) {
  unsigned int u = __float_as_uint(f);
  u += 0x7fffu + ((u >> 16) & 1u);
  return (unsigned short)(u >> 16);
}
__device__ __forceinline__ float bf2f(unsigned short h) {
  return __uint_as_float(((unsigned int)h) << 16);
}

__device__ __forceinline__ void gl_lds16(const unsigned short* g, unsigned short* l) {
  __builtin_amdgcn_global_load_lds(
      (const __attribute__((address_space(1))) unsigned int*)g,
      (__attribute__((address_space(3))) unsigned int*)l,
      16, 0, 0);
}

#define SBR __builtin_amdgcn_sched_barrier(0)

// ---------------- LayerNorm: fp32 [16384,1152] -> bf16 ----------------
__global__ __launch_bounds__(256) void ln_kernel(const float* __restrict__ x,
                                                 const float* __restrict__ gamma,
                                                 const float* __restrict__ beta,
                                                 unsigned short* __restrict__ xn) {
  const int row = blockIdx.x;
  const int tid = threadIdx.x;
  const float4* xr = (const float4*)(x + (size_t)row * D_);
  float4 v0 = xr[tid];
  float4 v1 = {0.f, 0.f, 0.f, 0.f};
  const bool has2 = tid < 32;
  if (has2) v1 = xr[256 + tid];
  float s  = v0.x + v0.y + v0.z + v0.w + v1.x + v1.y + v1.z + v1.w;
  float s2 = v0.x*v0.x + v0.y*v0.y + v0.z*v0.z + v0.w*v0.w
           + v1.x*v1.x + v1.y*v1.y + v1.z*v1.z + v1.w*v1.w;
#pragma unroll
  for (int o = 32; o > 0; o >>= 1) { s += __shfl_down(s, o); s2 += __shfl_down(s2, o); }
  __shared__ float red[8];
  int wid = tid >> 6, lane = tid & 63;
  if (lane == 0) { red[wid] = s; red[4 + wid] = s2; }
  __syncthreads();
  float ts  = red[0] + red[1] + red[2] + red[3];
  float ts2 = red[4] + red[5] + red[6] + red[7];
  const float inv = 1.f / (float)D_;
  float mean = ts * inv;
  float var  = ts2 * inv - mean * mean;
  float rstd = rsqrtf(var + 1e-6f);
  const float4* gm = (const float4*)gamma;
  const float4* bt = (const float4*)beta;
  unsigned short* xo = xn + (size_t)row * D_;
  {
    float4 gv = gm[tid], bv = bt[tid];
    u16x4 r;
    r[0] = f2bf((v0.x - mean) * rstd * gv.x + bv.x);
    r[1] = f2bf((v0.y - mean) * rstd * gv.y + bv.y);
    r[2] = f2bf((v0.z - mean) * rstd * gv.z + bv.z);
    r[3] = f2bf((v0.w - mean) * rstd * gv.w + bv.w);
    *(u16x4*)(xo + tid * 4) = r;
  }
  if (has2) {
    float4 gv = gm[256 + tid], bv = bt[256 + tid];
    u16x4 r;
    r[0] = f2bf((v1.x - mean) * rstd * gv.x + bv.x);
    r[1] = f2bf((v1.y - mean) * rstd * gv.y + bv.y);
    r[2] = f2bf((v1.z - mean) * rstd * gv.z + bv.z);
    r[3] = f2bf((v1.w - mean) * rstd * gv.w + bv.w);
    *(u16x4*)(xo + (256 + tid) * 4) = r;
  }
}

// ---------------- Merged weight convert, head-permuted QKVG ----------------
__global__ void cvt_all(const float* __restrict__ Wq, const float* __restrict__ Wk,
                        const float* __restrict__ Wv, const float* __restrict__ Wg,
                        const float* __restrict__ Wo,
                        const float* __restrict__ bq, const float* __restrict__ bk,
                        const float* __restrict__ bv, const float* __restrict__ bg,
                        unsigned short* __restrict__ oQ, unsigned short* __restrict__ oO,
                        float* __restrict__ ob) {
  int i = blockIdx.x * 256 + threadIdx.x;
  const int n1 = 1536 * 384;
  const int n2 = 1152 * 1152;
  if (i < n1) {
    int r = i / 384, c = i - r * 384;
    int h = r / 96, pp = (r / 24) & 3, d = r % 24;
    const float* W = (pp == 0) ? Wq : (pp == 1) ? Wk : (pp == 2) ? Wv : Wg;
    oQ[i] = f2bf(W[(h * 24 + d) * 384 + c]);
  } else if (i < n1 + n2) {
    int j = i - n1;
    oO[j] = f2bf(Wo[j]);
  } else if (i < n1 + n2 + 1536) {
    int r = i - n1 - n2;
    int h = r / 96, pp = (r / 24) & 3, d = r % 24;
    const float* bp = (pp == 0) ? bq : (pp == 1) ? bk : (pp == 2) ? bv : bg;
    ob[r] = bp[h * 24 + d];
  }
}

// ---------------- gemm1 fused with 3x3 attention + gate, BK=64 (R15) ----------------
__global__ __launch_bounds__(512) void gemm1_fused(
    const unsigned short* __restrict__ A, const unsigned short* __restrict__ Bp,
    unsigned short* __restrict__ Hout, const float* __restrict__ bperm) {
  const int K = 384;
  __shared__ __align__(16) unsigned short smem[2 * 18432];  // 73728 B
  const int tid = threadIdx.x;
  const int nwg = gridDim.x * gridDim.y;
  const int flat = blockIdx.y * gridDim.x + blockIdx.x;
  const int swz = (flat & 7) * (nwg >> 3) + (flat >> 3);
  const int bn = swz % gridDim.x, bm = swz / gridDim.x;   // bn = head

  const int wid = tid >> 6, lane = tid & 63;
  const int wm = wid >> 1, wn = wid & 1;       // 4M x 2N, wave-tile 48x48
  const int lrow = lane & 15, kq = lane >> 4;
  const int glc = (((lane & 7) ^ ((lane >> 3) & 7)) * 8);   // stage source chunk

  const unsigned short* Ab = A + (size_t)bm * 192 * K;
  const unsigned short* Bb = Bp + (size_t)bn * 96 * K;

  f32x4 acc[3][3];
#pragma unroll
  for (int m = 0; m < 3; ++m)
#pragma unroll
    for (int n = 0; n < 3; ++n) acc[m][n] = (f32x4){0.f, 0.f, 0.f, 0.f};

  int aoff[3][2], boff[3][2];
#pragma unroll
  for (int m = 0; m < 3; ++m) {
    const int row = wm * 48 + m * 16 + lrow;
#pragma unroll
    for (int s = 0; s < 2; ++s)
      aoff[m][s] = row * 128 + (((s * 4 + kq) ^ (lrow & 7)) * 16);
  }
#pragma unroll
  for (int n = 0; n < 3; ++n) {
    const int row = wn * 48 + n * 16 + lrow;
#pragma unroll
    for (int s = 0; s < 2; ++s)
      boff[n][s] = 24576 + row * 128 + (((s * 4 + kq) ^ (lrow & 7)) * 16);
  }

#define STG1U(J, kt, u)                                                       \
  {                                                                           \
    const unsigned short* src;                                                \
    if ((u) < 24) src = Ab + (size_t)((u) * 8 + (lane >> 3)) * K + (kt) * 64 + glc; \
    else          src = Bb + (size_t)(((u) - 24) * 8 + (lane >> 3)) * K + (kt) * 64 + glc; \
    gl_lds16(src, smem + (J) * 18432 + (u) * 512);                            \
  }

#define STAGE1(J, kt)                                                         \
  {                                                                           \
    STG1U(J, kt, wid);                                                        \
    STG1U(J, kt, wid + 8);                                                    \
    STG1U(J, kt, wid + 16);                                                   \
    STG1U(J, kt, wid + 24);                                                   \
    if (wid < 4) STG1U(J, kt, wid + 32);                                      \
  }

#define KSTEP1(J, kt, DOSTAGE)                                                \
  {                                                                           \
    if (DOSTAGE) STAGE1((J) ^ 1, (kt) + 1);                                   \
    bf16x8 af[3][2], bfr[3][2];                                               \
    _Pragma("unroll")                                                         \
    for (int m = 0; m < 3; ++m)                                               \
      _Pragma("unroll")                                                       \
      for (int s = 0; s < 2; ++s)                                             \
        af[m][s] = *(const bf16x8*)((const char*)smem + (J) * 36864 + aoff[m][s]); \
    _Pragma("unroll")                                                         \
    for (int n = 0; n < 3; ++n)                                               \
      _Pragma("unroll")                                                       \
      for (int s = 0; s < 2; ++s)                                             \
        bfr[n][s] = *(const bf16x8*)((const char*)smem + (J) * 36864 + boff[n][s]); \
    asm volatile("s_waitcnt lgkmcnt(0)" ::: "memory");                        \
    SBR;                                                                      \
    __builtin_amdgcn_s_setprio(1);                                            \
    _Pragma("unroll")                                                         \
    for (int s = 0; s < 2; ++s)                                               \
      _Pragma("unroll")                                                       \
      for (int m = 0; m < 3; ++m)                                             \
        _Pragma("unroll")                                                     \
        for (int n = 0; n < 3; ++n)                                           \
          acc[m][n] = __builtin_amdgcn_mfma_f32_16x16x32_bf16(af[m][s], bfr[n][s], \
                                                              acc[m][n], 0,0,0); \
    __builtin_amdgcn_s_setprio(0);                                            \
    asm volatile("s_waitcnt vmcnt(0)" ::: "memory");                          \
    SBR;                                                                      \
    __builtin_amdgcn_s_barrier();                                             \
    SBR;                                                                      \
  }

  STAGE1(0, 0);
  asm volatile("s_waitcnt vmcnt(0)" ::: "memory");
  SBR;
  __builtin_amdgcn_s_barrier();
  SBR;

#pragma unroll 1
  for (int t = 0; t < 6; t += 2) {
    KSTEP1(0, t, true);
    KSTEP1(1, t + 1, (t + 2 < 6));
  }
#undef KSTEP1
#undef STAGE1
#undef STG1U

  // ---- epilogue part 1: acc (+bias) -> smem[192][stride 104] bf16 ----
  const int EPS = 104;
#pragma unroll
  for (int m = 0; m < 3; ++m) {
#pragma unroll
    for (int n = 0; n < 3; ++n) {
      const int col = wn * 48 + n * 16 + lrow;
      const float bb = bperm[bn * 96 + col];
#pragma unroll
      for (int i = 0; i < 4; ++i) {
        const int row = wm * 48 + m * 16 + kq * 4 + i;
        smem[row * EPS + col] = f2bf(acc[m][n][i] + bb);
      }
    }
  }
  __syncthreads();

  // ---- epilogue part 2: per-(token,group) 3x3 attention + gate ----
  if (tid < 192) {
    const int tl = tid / 3;
    const int gi = tid - tl * 3;
    const unsigned short* rowq = smem + tid * EPS;
    float q[24], o[24];
#pragma unroll
    for (int c = 0; c < 3; ++c) {
      u16x8 w = *(const u16x8*)(rowq + c * 8);
#pragma unroll
      for (int e = 0; e < 8; ++e) q[c * 8 + e] = bf2f(w[e]);
    }
    float s[3];
#pragma unroll
    for (int j = 0; j < 3; ++j) {
      const unsigned short* rk = smem + (tl * 3 + j) * EPS + 24;
      float a = 0.f;
#pragma unroll
      for (int c = 0; c < 3; ++c) {
        u16x8 w = *(const u16x8*)(rk + c * 8);
#pragma unroll
        for (int e = 0; e < 8; ++e) a += q[c * 8 + e] * bf2f(w[e]);
      }
      s[j] = a * 0.11785113019775793f;
    }
    float mx = fmaxf(s[0], fmaxf(s[1], s[2]));
    float e0 = __expf(s[0] - mx), e1 = __expf(s[1] - mx), e2 = __expf(s[2] - mx);
    float inv = 1.f / (e0 + e1 + e2);
    float pj[3] = {e0 * inv, e1 * inv, e2 * inv};
#pragma unroll
    for (int d = 0; d < 24; ++d) o[d] = 0.f;
#pragma unroll
    for (int j = 0; j < 3; ++j) {
      const unsigned short* rv = smem + (tl * 3 + j) * EPS + 48;
#pragma unroll
      for (int c = 0; c < 3; ++c) {
        u16x8 w = *(const u16x8*)(rv + c * 8);
#pragma unroll
        for (int e = 0; e < 8; ++e) o[c * 8 + e] += pj[j] * bf2f(w[e]);
      }
    }
    const int t = bm * 64 + tl;
    unsigned short* op = Hout + (size_t)t * 1152 + gi * 384 + bn * 24;
#pragma unroll
    for (int c = 0; c < 3; ++c) {
      u16x8 w = *(const u16x8*)(rowq + 72 + c * 8);
      u16x8 r;
#pragma unroll
      for (int e = 0; e < 8; ++e) {
        float gvv = bf2f(w[e]);
        float sg = 1.f / (1.f + __expf(-gvv));
        r[e] = f2bf(o[c * 8 + e] * sg);
      }
      *(u16x8*)(op + c * 8) = r;
    }
  }
}

// ---------------- gemm2: out = Hf @ Wo^T + bo + x*g, BK=64, exact 3 rounds ----------------
// BM=128, BN=96, BK=64. 384 thr = 6 waves (2M x 3N), wave-tile 64x32
// (4x2 frags x 2 k-halves = 16 MFMA/step). nk=18. dbuf-2 LDS = 57.3KB ->
// 2 blocks/CU = 512 resident; grid 1536 = EXACTLY 3 rounds (no tail).
// Same 128B-row swizzle pair as gemm1_fused (R15 refcheck-validated).

__global__ __launch_bounds__(384) void gemm2_64(
    const unsigned short* __restrict__ A, const unsigned short* __restrict__ Bt,
    float* __restrict__ Cf, const float* __restrict__ bo,
    const float* __restrict__ xres, const float* __restrict__ gs) {
  const int K = 1152, N = 1152;
  __shared__ __align__(16) unsigned short smem[2 * 14336];  // 57344 B
  const int tid = threadIdx.x;
  const int nwg = gridDim.x * gridDim.y;
  const int flat = blockIdx.y * gridDim.x + blockIdx.x;
  const int swz = (flat & 7) * (nwg >> 3) + (flat >> 3);
  const int bn = swz % gridDim.x, bm = swz / gridDim.x;

  const int wid = tid >> 6, lane = tid & 63;
  const int wm = wid / 3, wn = wid % 3;        // 2M x 3N, wave-tile 64x32
  const int lrow = lane & 15, kq = lane >> 4;
  const int glc = (((lane & 7) ^ ((lane >> 3) & 7)) * 8);   // stage source chunk

  const unsigned short* Ab = A + (size_t)bm * 128 * K;
  const unsigned short* Bb = Bt + (size_t)bn * 96 * K;

  f32x4 acc[4][2];
#pragma unroll
  for (int m = 0; m < 4; ++m)
#pragma unroll
    for (int n = 0; n < 2; ++n) acc[m][n] = (f32x4){0.f, 0.f, 0.f, 0.f};

  // read byte-offsets (within slot): row*128 + ((s*4+kq)^(row&7))*16
  int aoff[4][2], boff[2][2];
#pragma unroll
  for (int m = 0; m < 4; ++m) {
    const int row = wm * 64 + m * 16 + lrow;
#pragma unroll
    for (int s = 0; s < 2; ++s)
      aoff[m][s] = row * 128 + (((s * 4 + kq) ^ (lrow & 7)) * 16);
  }
#pragma unroll
  for (int n = 0; n < 2; ++n) {
    const int row = wn * 32 + n * 16 + lrow;
#pragma unroll
    for (int s = 0; s < 2; ++s)
      boff[n][s] = 16384 + row * 128 + (((s * 4 + kq) ^ (lrow & 7)) * 16);
  }

  // 28 stage units of 1KB (8 rows x 64): u<16 -> A rows u*8; else B rows (u-16)*8.
#define STG2U(J, kt, u)                                                       \
  {                                                                           \
    const unsigned short* src;                                                \
    if ((u) < 16) src = Ab + (size_t)((u) * 8 + (lane >> 3)) * K + (kt) * 64 + glc; \
    else          src = Bb + (size_t)(((u) - 16) * 8 + (lane >> 3)) * K + (kt) * 64 + glc; \
    gl_lds16(src, smem + (J) * 14336 + (u) * 512);                            \
  }

#define STAGE2(J, kt)                                                         \
  {                                                                           \
    STG2U(J, kt, wid);                                                        \
    STG2U(J, kt, wid + 6);                                                    \
    STG2U(J, kt, wid + 12);                                                   \
    STG2U(J, kt, wid + 18);                                                   \
    if (wid < 4) STG2U(J, kt, wid + 24);                                      \
  }

#define KSTEP2(J, kt, DOSTAGE)                                                \
  {                                                                           \
    if (DOSTAGE) STAGE2((J) ^ 1, (kt) + 1);                                   \
    bf16x8 af[4][2], bfr[2][2];                                               \
    _Pragma("unroll")                                                         \
    for (int m = 0; m < 4; ++m)                                               \
      _Pragma("unroll")                                                       \
      for (int s = 0; s < 2; ++s)                                             \
        af[m][s] = *(const bf16x8*)((const char*)smem + (J) * 28672 + aoff[m][s]); \
    _Pragma("unroll")                                                         \
    for (int n = 0; n < 2; ++n)                                               \
      _Pragma("unroll")                                                       \
      for (int s = 0; s < 2; ++s)                                             \
        bfr[n][s] = *(const bf16x8*)((const char*)smem + (J) * 28672 + boff[n][s]); \
    asm volatile("s_waitcnt lgkmcnt(0)" ::: "memory");                        \
    SBR;                                                                      \
    __builtin_amdgcn_s_setprio(1);                                            \
    _Pragma("unroll")                                                         \
    for (int s = 0; s < 2; ++s)                                               \
      _Pragma("unroll")                                                       \
      for (int m = 0; m < 4; ++m)                                             \
        _Pragma("unroll")                                                     \
        for (int n = 0; n < 2; ++n)                                           \
          acc[m][n] = __builtin_amdgcn_mfma_f32_16x16x32_bf16(af[m][s], bfr[n][s], \
                                                              acc[m][n], 0,0,0); \
    __builtin_amdgcn_s_setprio(0);                                            \
    asm volatile("s_waitcnt vmcnt(0)" ::: "memory");                          \
    SBR;                                                                      \
    __builtin_amdgcn_s_barrier();                                             \
    SBR;                                                                      \
  }

  STAGE2(0, 0);
  asm volatile("s_waitcnt vmcnt(0)" ::: "memory");
  SBR;
  __builtin_amdgcn_s_barrier();
  SBR;

#pragma unroll 1
  for (int t = 0; t < 18; t += 2) {
    KSTEP2(0, t, true);
    KSTEP2(1, t + 1, (t + 2 < 18));
  }
#undef KSTEP2
#undef STAGE2
#undef STG2U

  // Epilogue. D layout: col = lane&15, row = (lane>>4)*4 + reg  [m89-verified]
  const int rbase = bm * 128 + wm * 64 + kq * 4;
  const int cbase = bn * 96 + wn * 32 + lrow;
  float gv = gs[0];
#pragma unroll
  for (int m = 0; m < 4; ++m) {
#pragma unroll
    for (int n = 0; n < 2; ++n) {
      int col = cbase + n * 16;
      float bias = bo[col];
#pragma unroll
      for (int i = 0; i < 4; ++i) {
        int row = rbase + m * 16 + i;
        size_t idx = (size_t)row * N + col;
        Cf[idx] = acc[m][n][i] + bias + xres[idx] * gv;
      }
    }
  }
}

extern "C" void kernel_launch(void* const* d_in, const int* in_sizes, int n_in,
                              void* d_out, int out_size, void* d_ws, size_t ws_size,
                              hipStream_t stream) {
  const float* x    = (const float*)d_in[0];
  const float* ln_g = (const float*)d_in[1];
  const float* ln_b = (const float*)d_in[2];
  const float* Wq   = (const float*)d_in[3];
  const float* bq   = (const float*)d_in[4];
  const float* Wk   = (const float*)d_in[5];
  const float* bk   = (const float*)d_in[6];
  const float* Wv   = (const float*)d_in[7];
  const float* bv   = (const float*)d_in[8];
  const float* Wg   = (const float*)d_in[9];
  const float* bg   = (const float*)d_in[10];
  const float* Wo   = (const float*)d_in[11];
  const float* bo   = (const float*)d_in[12];
  const float* g    = (const float*)d_in[13];
  float* out = (float*)d_out;

  char* ws = (char*)d_ws;
  size_t off = 0;
  unsigned short* xn    = (unsigned short*)(ws + off); off += (size_t)T_ * D_ * 2;
  unsigned short* Wqkvg = (unsigned short*)(ws + off); off += (size_t)1536 * 384 * 2;
  unsigned short* Wob   = (unsigned short*)(ws + off); off += (size_t)1152 * 1152 * 2;
  float*          bperm = (float*)(ws + off);          off += 1536 * 4;
  unsigned short* Hf    = (unsigned short*)(ws + off); off += (size_t)T_ * D_ * 2;

  ln_kernel<<<T_, 256, 0, stream>>>(x, ln_g, ln_b, xn);
  const int ncvt = 1536 * 384 + 1152 * 1152 + 1536;
  cvt_all<<<(ncvt + 255) / 256, 256, 0, stream>>>(Wq, Wk, Wv, Wg, Wo,
                                                  bq, bk, bv, bg,
                                                  Wqkvg, Wob, bperm);

  dim3 g1(16, (T_ * 3) / 192);   // (16 heads, 256 M-blocks) nwg=4096 = 8.0 rounds
  gemm1_fused<<<g1, 512, 0, stream>>>(xn, Wqkvg, Hf, bperm);

  dim3 g2(1152 / 96, T_ / 128);  // (12, 128) nwg=1536 = 3.0 rounds @2/CU
  gemm2_64<<<g2, 384, 0, stream>>>(Hf, Wob, out, bo, x, g);
}

// Round 17
// 187.184 us; speedup vs baseline: 1.1058x; 1.1058x over previous
//
#include <hip/hip_runtime.h>

#define B_ 4
#define L_ 4096
#define D_ 1152
#define T_ (B_*L_)      // 16384 tokens
#define D3_ 384
#define H_ 16

typedef __attribute__((ext_vector_type(4))) float f32x4;
typedef __attribute__((ext_vector_type(8))) __bf16 bf16x8;
typedef __attribute__((ext_vector_type(8))) unsigned short u16x8;
typedef __attribute__((ext_vector_type(4))) unsigned short u16x4;

__device__ __forceinline__ unsigned short f2bf(float f) {
  unsigned int u = __float_as_uint(f);
  u += 0x7fffu + ((u >> 16) & 1u);
  return (unsigned short)(u >> 16);
}
__device__ __forceinline__ float bf2f(unsigned short h) {
  return __uint_as_float(((unsigned int)h) << 16);
}

__device__ __forceinline__ void gl_lds16(const unsigned short* g, unsigned short* l) {
  __builtin_amdgcn_global_load_lds(
      (const __attribute__((address_space(1))) unsigned int*)g,
      (__attribute__((address_space(3))) unsigned int*)l,
      16, 0, 0);
}

#define SBR __builtin_amdgcn_sched_barrier(0)

// ---------------- LayerNorm: fp32 [16384,1152] -> bf16 ----------------
__global__ __launch_bounds__(256) void ln_kernel(const float* __restrict__ x,
                                                 const float* __restrict__ gamma,
                                                 const float* __restrict__ beta,
                                                 unsigned short* __restrict__ xn) {
  const int row = blockIdx.x;
  const int tid = threadIdx.x;
  const float4* xr = (const float4*)(x + (size_t)row * D_);
  float4 v0 = xr[tid];
  float4 v1 = {0.f, 0.f, 0.f, 0.f};
  const bool has2 = tid < 32;
  if (has2) v1 = xr[256 + tid];
  float s  = v0.x + v0.y + v0.z + v0.w + v1.x + v1.y + v1.z + v1.w;
  float s2 = v0.x*v0.x + v0.y*v0.y + v0.z*v0.z + v0.w*v0.w
           + v1.x*v1.x + v1.y*v1.y + v1.z*v1.z + v1.w*v1.w;
#pragma unroll
  for (int o = 32; o > 0; o >>= 1) { s += __shfl_down(s, o); s2 += __shfl_down(s2, o); }
  __shared__ float red[8];
  int wid = tid >> 6, lane = tid & 63;
  if (lane == 0) { red[wid] = s; red[4 + wid] = s2; }
  __syncthreads();
  float ts  = red[0] + red[1] + red[2] + red[3];
  float ts2 = red[4] + red[5] + red[6] + red[7];
  const float inv = 1.f / (float)D_;
  float mean = ts * inv;
  float var  = ts2 * inv - mean * mean;
  float rstd = rsqrtf(var + 1e-6f);
  const float4* gm = (const float4*)gamma;
  const float4* bt = (const float4*)beta;
  unsigned short* xo = xn + (size_t)row * D_;
  {
    float4 gv = gm[tid], bv = bt[tid];
    u16x4 r;
    r[0] = f2bf((v0.x - mean) * rstd * gv.x + bv.x);
    r[1] = f2bf((v0.y - mean) * rstd * gv.y + bv.y);
    r[2] = f2bf((v0.z - mean) * rstd * gv.z + bv.z);
    r[3] = f2bf((v0.w - mean) * rstd * gv.w + bv.w);
    *(u16x4*)(xo + tid * 4) = r;
  }
  if (has2) {
    float4 gv = gm[256 + tid], bv = bt[256 + tid];
    u16x4 r;
    r[0] = f2bf((v1.x - mean) * rstd * gv.x + bv.x);
    r[1] = f2bf((v1.y - mean) * rstd * gv.y + bv.y);
    r[2] = f2bf((v1.z - mean) * rstd * gv.z + bv.z);
    r[3] = f2bf((v1.w - mean) * rstd * gv.w + bv.w);
    *(u16x4*)(xo + (256 + tid) * 4) = r;
  }
}

// ---------------- Merged weight convert, head-permuted QKVG ----------------
__global__ void cvt_all(const float* __restrict__ Wq, const float* __restrict__ Wk,
                        const float* __restrict__ Wv, const float* __restrict__ Wg,
                        const float* __restrict__ Wo,
                        const float* __restrict__ bq, const float* __restrict__ bk,
                        const float* __restrict__ bv, const float* __restrict__ bg,
                        unsigned short* __restrict__ oQ, unsigned short* __restrict__ oO,
                        float* __restrict__ ob) {
  int i = blockIdx.x * 256 + threadIdx.x;
  const int n1 = 1536 * 384;
  const int n2 = 1152 * 1152;
  if (i < n1) {
    int r = i / 384, c = i - r * 384;
    int h = r / 96, pp = (r / 24) & 3, d = r % 24;
    const float* W = (pp == 0) ? Wq : (pp == 1) ? Wk : (pp == 2) ? Wv : Wg;
    oQ[i] = f2bf(W[(h * 24 + d) * 384 + c]);
  } else if (i < n1 + n2) {
    int j = i - n1;
    oO[j] = f2bf(Wo[j]);
  } else if (i < n1 + n2 + 1536) {
    int r = i - n1 - n2;
    int h = r / 96, pp = (r / 24) & 3, d = r % 24;
    const float* bp = (pp == 0) ? bq : (pp == 1) ? bk : (pp == 2) ? bv : bg;
    ob[r] = bp[h * 24 + d];
  }
}

// ---------------- gemm1 fused with 3x3 attention + gate, BK=64 ----------------
// R15 loop unchanged. Epilogue part 2 now 2-way split: 384 threads, each
// handles 12 dims of one (token,group); q.k dots combined via shfl_xor(,1).

__global__ __launch_bounds__(512) void gemm1_fused(
    const unsigned short* __restrict__ A, const unsigned short* __restrict__ Bp,
    unsigned short* __restrict__ Hout, const float* __restrict__ bperm) {
  const int K = 384;
  __shared__ __align__(16) unsigned short smem[2 * 18432];  // 73728 B
  const int tid = threadIdx.x;
  const int nwg = gridDim.x * gridDim.y;
  const int flat = blockIdx.y * gridDim.x + blockIdx.x;
  const int swz = (flat & 7) * (nwg >> 3) + (flat >> 3);
  const int bn = swz % gridDim.x, bm = swz / gridDim.x;   // bn = head

  const int wid = tid >> 6, lane = tid & 63;
  const int wm = wid >> 1, wn = wid & 1;       // 4M x 2N, wave-tile 48x48
  const int lrow = lane & 15, kq = lane >> 4;
  const int glc = (((lane & 7) ^ ((lane >> 3) & 7)) * 8);   // stage source chunk

  const unsigned short* Ab = A + (size_t)bm * 192 * K;
  const unsigned short* Bb = Bp + (size_t)bn * 96 * K;

  f32x4 acc[3][3];
#pragma unroll
  for (int m = 0; m < 3; ++m)
#pragma unroll
    for (int n = 0; n < 3; ++n) acc[m][n] = (f32x4){0.f, 0.f, 0.f, 0.f};

  int aoff[3][2], boff[3][2];
#pragma unroll
  for (int m = 0; m < 3; ++m) {
    const int row = wm * 48 + m * 16 + lrow;
#pragma unroll
    for (int s = 0; s < 2; ++s)
      aoff[m][s] = row * 128 + (((s * 4 + kq) ^ (lrow & 7)) * 16);
  }
#pragma unroll
  for (int n = 0; n < 3; ++n) {
    const int row = wn * 48 + n * 16 + lrow;
#pragma unroll
    for (int s = 0; s < 2; ++s)
      boff[n][s] = 24576 + row * 128 + (((s * 4 + kq) ^ (lrow & 7)) * 16);
  }

#define STG1U(J, kt, u)                                                       \
  {                                                                           \
    const unsigned short* src;                                                \
    if ((u) < 24) src = Ab + (size_t)((u) * 8 + (lane >> 3)) * K + (kt) * 64 + glc; \
    else          src = Bb + (size_t)(((u) - 24) * 8 + (lane >> 3)) * K + (kt) * 64 + glc; \
    gl_lds16(src, smem + (J) * 18432 + (u) * 512);                            \
  }

#define STAGE1(J, kt)                                                         \
  {                                                                           \
    STG1U(J, kt, wid);                                                        \
    STG1U(J, kt, wid + 8);                                                    \
    STG1U(J, kt, wid + 16);                                                   \
    STG1U(J, kt, wid + 24);                                                   \
    if (wid < 4) STG1U(J, kt, wid + 32);                                      \
  }

#define KSTEP1(J, kt, DOSTAGE)                                                \
  {                                                                           \
    if (DOSTAGE) STAGE1((J) ^ 1, (kt) + 1);                                   \
    bf16x8 af[3][2], bfr[3][2];                                               \
    _Pragma("unroll")                                                         \
    for (int m = 0; m < 3; ++m)                                               \
      _Pragma("unroll")                                                       \
      for (int s = 0; s < 2; ++s)                                             \
        af[m][s] = *(const bf16x8*)((const char*)smem + (J) * 36864 + aoff[m][s]); \
    _Pragma("unroll")                                                         \
    for (int n = 0; n < 3; ++n)                                               \
      _Pragma("unroll")                                                       \
      for (int s = 0; s < 2; ++s)                                             \
        bfr[n][s] = *(const bf16x8*)((const char*)smem + (J) * 36864 + boff[n][s]); \
    asm volatile("s_waitcnt lgkmcnt(0)" ::: "memory");                        \
    SBR;                                                                      \
    __builtin_amdgcn_s_setprio(1);                                            \
    _Pragma("unroll")                                                         \
    for (int s = 0; s < 2; ++s)                                               \
      _Pragma("unroll")                                                       \
      for (int m = 0; m < 3; ++m)                                             \
        _Pragma("unroll")                                                     \
        for (int n = 0; n < 3; ++n)                                           \
          acc[m][n] = __builtin_amdgcn_mfma_f32_16x16x32_bf16(af[m][s], bfr[n][s], \
                                                              acc[m][n], 0,0,0); \
    __builtin_amdgcn_s_setprio(0);                                            \
    asm volatile("s_waitcnt vmcnt(0)" ::: "memory");                          \
    SBR;                                                                      \
    __builtin_amdgcn_s_barrier();                                             \
    SBR;                                                                      \
  }

  STAGE1(0, 0);
  asm volatile("s_waitcnt vmcnt(0)" ::: "memory");
  SBR;
  __builtin_amdgcn_s_barrier();
  SBR;

#pragma unroll 1
  for (int t = 0; t < 6; t += 2) {
    KSTEP1(0, t, true);
    KSTEP1(1, t + 1, (t + 2 < 6));
  }
#undef KSTEP1
#undef STAGE1
#undef STG1U

  // ---- epilogue part 1: acc (+bias) -> smem[192][stride 104] bf16 ----
  const int EPS = 104;
#pragma unroll
  for (int m = 0; m < 3; ++m) {
#pragma unroll
    for (int n = 0; n < 3; ++n) {
      const int col = wn * 48 + n * 16 + lrow;
      const float bb = bperm[bn * 96 + col];
#pragma unroll
      for (int i = 0; i < 4; ++i) {
        const int row = wm * 48 + m * 16 + kq * 4 + i;
        smem[row * EPS + col] = f2bf(acc[m][n][i] + bb);
      }
    }
  }
  __syncthreads();

  // ---- epilogue part 2: 384 threads, 2 per (token,group), 12 dims each ----
  if (tid < 384) {
    const int item = tid >> 1;         // 0..191
    const int w = tid & 1;             // half: dims [w*12, w*12+12)
    const int tl = item / 3;           // local token 0..63
    const int gi = item - tl * 3;      // group i
    const unsigned short* rowq = smem + item * EPS;
    const int dw = w * 12;

    float q[12];
#pragma unroll
    for (int c = 0; c < 3; ++c) {
      u16x4 v = *(const u16x4*)(rowq + dw + c * 4);
#pragma unroll
      for (int e = 0; e < 4; ++e) q[c * 4 + e] = bf2f(v[e]);
    }
    float s[3];
#pragma unroll
    for (int j = 0; j < 3; ++j) {
      const unsigned short* rk = smem + (tl * 3 + j) * EPS + 24 + dw;
      float a = 0.f;
#pragma unroll
      for (int c = 0; c < 3; ++c) {
        u16x4 v = *(const u16x4*)(rk + c * 4);
#pragma unroll
        for (int e = 0; e < 4; ++e) a += q[c * 4 + e] * bf2f(v[e]);
      }
      s[j] = a;
    }
    // combine halves (partner = tid^1, same wave)
#pragma unroll
    for (int j = 0; j < 3; ++j) {
      s[j] += __shfl_xor(s[j], 1);
      s[j] *= 0.11785113019775793f;    // 1/sqrt(72)
    }
    float mx = fmaxf(s[0], fmaxf(s[1], s[2]));
    float e0 = __expf(s[0] - mx), e1 = __expf(s[1] - mx), e2 = __expf(s[2] - mx);
    float inv = 1.f / (e0 + e1 + e2);
    float pj[3] = {e0 * inv, e1 * inv, e2 * inv};

    float o[12];
#pragma unroll
    for (int d = 0; d < 12; ++d) o[d] = 0.f;
#pragma unroll
    for (int j = 0; j < 3; ++j) {
      const unsigned short* rv = smem + (tl * 3 + j) * EPS + 48 + dw;
#pragma unroll
      for (int c = 0; c < 3; ++c) {
        u16x4 v = *(const u16x4*)(rv + c * 4);
#pragma unroll
        for (int e = 0; e < 4; ++e) o[c * 4 + e] += pj[j] * bf2f(v[e]);
      }
    }
    const int t = bm * 64 + tl;
    unsigned short* op = Hout + (size_t)t * 1152 + gi * 384 + bn * 24 + dw;
#pragma unroll
    for (int c = 0; c < 3; ++c) {
      u16x4 v = *(const u16x4*)(rowq + 72 + dw + c * 4);
      u16x4 r;
#pragma unroll
      for (int e = 0; e < 4; ++e) {
        float gvv = bf2f(v[e]);
        float sg = 1.f / (1.f + __expf(-gvv));
        r[e] = f2bf(o[c * 4 + e] * sg);
      }
      *(u16x4*)(op + c * 4) = r;
    }
  }
}

// ---------------- gemm2: out = Hf @ Wo^T + bo + x*g, BK=64, 8 waves ----------------
// BM=128, BN=96, BK=64. 512 thr = 8 waves (4M x 2N), wave-tile 32x48
// (2x3 frags x 2 k-halves = 12 MFMA/step). nk=18. dbuf-2 LDS = 57.3KB ->
// 2 blocks/CU = 16 waves/CU (vs R16's 12). Grid 1536 = exactly 3 rounds.

__global__ __launch_bounds__(512) void gemm2_64(
    const unsigned short* __restrict__ A, const unsigned short* __restrict__ Bt,
    float* __restrict__ Cf, const float* __restrict__ bo,
    const float* __restrict__ xres, const float* __restrict__ gs) {
  const int K = 1152, N = 1152;
  __shared__ __align__(16) unsigned short smem[2 * 14336];  // 57344 B
  const int tid = threadIdx.x;
  const int nwg = gridDim.x * gridDim.y;
  const int flat = blockIdx.y * gridDim.x + blockIdx.x;
  const int swz = (flat & 7) * (nwg >> 3) + (flat >> 3);
  const int bn = swz % gridDim.x, bm = swz / gridDim.x;

  const int wid = tid >> 6, lane = tid & 63;
  const int wm = wid >> 1, wn = wid & 1;       // 4M x 2N, wave-tile 32x48
  const int lrow = lane & 15, kq = lane >> 4;
  const int glc = (((lane & 7) ^ ((lane >> 3) & 7)) * 8);   // stage source chunk

  const unsigned short* Ab = A + (size_t)bm * 128 * K;
  const unsigned short* Bb = Bt + (size_t)bn * 96 * K;

  f32x4 acc[2][3];
#pragma unroll
  for (int m = 0; m < 2; ++m)
#pragma unroll
    for (int n = 0; n < 3; ++n) acc[m][n] = (f32x4){0.f, 0.f, 0.f, 0.f};

  // read byte-offsets (within slot): row*128 + ((s*4+kq)^(row&7))*16
  int aoff[2][2], boff[3][2];
#pragma unroll
  for (int m = 0; m < 2; ++m) {
    const int row = wm * 32 + m * 16 + lrow;
#pragma unroll
    for (int s = 0; s < 2; ++s)
      aoff[m][s] = row * 128 + (((s * 4 + kq) ^ (lrow & 7)) * 16);
  }
#pragma unroll
  for (int n = 0; n < 3; ++n) {
    const int row = wn * 48 + n * 16 + lrow;
#pragma unroll
    for (int s = 0; s < 2; ++s)
      boff[n][s] = 16384 + row * 128 + (((s * 4 + kq) ^ (lrow & 7)) * 16);
  }

  // 28 stage units of 1KB (8 rows x 64): u<16 -> A rows u*8; else B rows (u-16)*8.
#define STG2U(J, kt, u)                                                       \
  {                                                                           \
    const unsigned short* src;                                                \
    if ((u) < 16) src = Ab + (size_t)((u) * 8 + (lane >> 3)) * K + (kt) * 64 + glc; \
    else          src = Bb + (size_t)(((u) - 16) * 8 + (lane >> 3)) * K + (kt) * 64 + glc; \
    gl_lds16(src, smem + (J) * 14336 + (u) * 512);                            \
  }

#define STAGE2(J, kt)                                                         \
  {                                                                           \
    STG2U(J, kt, wid);                                                        \
    STG2U(J, kt, wid + 8);                                                    \
    STG2U(J, kt, wid + 16);                                                   \
    if (wid < 4) STG2U(J, kt, wid + 24);                                      \
  }

#define KSTEP2(J, kt, DOSTAGE)                                                \
  {                                                                           \
    if (DOSTAGE) STAGE2((J) ^ 1, (kt) + 1);                                   \
    bf16x8 af[2][2], bfr[3][2];                                               \
    _Pragma("unroll")                                                         \
    for (int m = 0; m < 2; ++m)                                               \
      _Pragma("unroll")                                                       \
      for (int s = 0; s < 2; ++s)                                             \
        af[m][s] = *(const bf16x8*)((const char*)smem + (J) * 28672 + aoff[m][s]); \
    _Pragma("unroll")                                                         \
    for (int n = 0; n < 3; ++n)                                               \
      _Pragma("unroll")                                                       \
      for (int s = 0; s < 2; ++s)                                             \
        bfr[n][s] = *(const bf16x8*)((const char*)smem + (J) * 28672 + boff[n][s]); \
    asm volatile("s_waitcnt lgkmcnt(0)" ::: "memory");                        \
    SBR;                                                                      \
    __builtin_amdgcn_s_setprio(1);                                            \
    _Pragma("unroll")                                                         \
    for (int s = 0; s < 2; ++s)                                               \
      _Pragma("unroll")                                                       \
      for (int m = 0; m < 2; ++m)                                             \
        _Pragma("unroll")                                                     \
        for (int n = 0; n < 3; ++n)                                           \
          acc[m][n] = __builtin_amdgcn_mfma_f32_16x16x32_bf16(af[m][s], bfr[n][s], \
                                                              acc[m][n], 0,0,0); \
    __builtin_amdgcn_s_setprio(0);                                            \
    asm volatile("s_waitcnt vmcnt(0)" ::: "memory");                          \
    SBR;                                                                      \
    __builtin_amdgcn_s_barrier();                                             \
    SBR;                                                                      \
  }

  STAGE2(0, 0);
  asm volatile("s_waitcnt vmcnt(0)" ::: "memory");
  SBR;
  __builtin_amdgcn_s_barrier();
  SBR;

#pragma unroll 1
  for (int t = 0; t < 18; t += 2) {
    KSTEP2(0, t, true);
    KSTEP2(1, t + 1, (t + 2 < 18));
  }
#undef KSTEP2
#undef STAGE2
#undef STG2U

  // Epilogue. D layout: col = lane&15, row = (lane>>4)*4 + reg  [m89-verified]
  const int rbase = bm * 128 + wm * 32 + kq * 4;
  const int cbase = bn * 96 + wn * 48 + lrow;
  float gv = gs[0];
#pragma unroll
  for (int m = 0; m < 2; ++m) {
#pragma unroll
    for (int n = 0; n < 3; ++n) {
      int col = cbase + n * 16;
      float bias = bo[col];
#pragma unroll
      for (int i = 0; i < 4; ++i) {
        int row = rbase + m * 16 + i;
        size_t idx = (size_t)row * N + col;
        Cf[idx] = acc[m][n][i] + bias + xres[idx] * gv;
      }
    }
  }
}

extern "C" void kernel_launch(void* const* d_in, const int* in_sizes, int n_in,
                              void* d_out, int out_size, void* d_ws, size_t ws_size,
                              hipStream_t stream) {
  const float* x    = (const float*)d_in[0];
  const float* ln_g = (const float*)d_in[1];
  const float* ln_b = (const float*)d_in[2];
  const float* Wq   = (const float*)d_in[3];
  const float* bq   = (const float*)d_in[4];
  const float* Wk   = (const float*)d_in[5];
  const float* bk   = (const float*)d_in[6];
  const float* Wv   = (const float*)d_in[7];
  const float* bv   = (const float*)d_in[8];
  const float* Wg   = (const float*)d_in[9];
  const float* bg   = (const float*)d_in[10];
  const float* Wo   = (const float*)d_in[11];
  const float* bo   = (const float*)d_in[12];
  const float* g    = (const float*)d_in[13];
  float* out = (float*)d_out;

  char* ws = (char*)d_ws;
  size_t off = 0;
  unsigned short* xn    = (unsigned short*)(ws + off); off += (size_t)T_ * D_ * 2;
  unsigned short* Wqkvg = (unsigned short*)(ws + off); off += (size_t)1536 * 384 * 2;
  unsigned short* Wob   = (unsigned short*)(ws + off); off += (size_t)1152 * 1152 * 2;
  float*          bperm = (float*)(ws + off);          off += 1536 * 4;
  unsigned short* Hf    = (unsigned short*)(ws + off); off += (size_t)T_ * D_ * 2;

  ln_kernel<<<T_, 256, 0, stream>>>(x, ln_g, ln_b, xn);
  const int ncvt = 1536 * 384 + 1152 * 1152 + 1536;
  cvt_all<<<(ncvt + 255) / 256, 256, 0, stream>>>(Wq, Wk, Wv, Wg, Wo,
                                                  bq, bk, bv, bg,
                                                  Wqkvg, Wob, bperm);

  dim3 g1(16, (T_ * 3) / 192);   // (16 heads, 256 M-blocks) nwg=4096 = 8.0 rounds
  gemm1_fused<<<g1, 512, 0, stream>>>(xn, Wqkvg, Hf, bperm);

  dim3 g2(1152 / 96, T_ / 128);  // (12, 128) nwg=1536 = 3.0 rounds @2/CU
  gemm2_64<<<g2, 512, 0, stream>>>(Hf, Wob, out, bo, x, g);
}